// Round 1
// baseline (213.239 us; speedup 1.0000x reference)
//
#include <hip/hip_runtime.h>
#include <stdint.h>

#define N_ANCH 67200
#define KCAP   1000
#define CONF_THR 0.7f
#define NMS_THR  0.4f
#define SLICES 8

// ---- workspace layout (bytes) ----
#define OFF_COUNTER 0
#define OFF_KEYS    64
#define OFF_RANK    (OFF_KEYS + N_ANCH*8)        // 537664
#define OFF_SCORE   (OFF_RANK + N_ANCH*4)        // 806464
#define OFF_BOX     (OFF_SCORE + 1024*4)         // 810560 (16B aligned)
#define OFF_LM      (OFF_BOX + 1024*4*4)         // 826944
#define OFF_SUP     (OFF_LM + 1024*10*4)         // 867904 (8B aligned)
// end = 867904 + 1000*16*8 = 995904 bytes (~0.95 MB of ws)

__device__ inline unsigned long long shfl_u64(unsigned long long v, int src) {
    unsigned int lo = (unsigned int)__shfl((int)(v & 0xffffffffull), src, 64);
    unsigned int hi = (unsigned int)__shfl((int)(v >> 32), src, 64);
    return ((unsigned long long)hi << 32) | lo;
}
__device__ inline unsigned long long shfl_xor_u64(unsigned long long v, int m) {
    unsigned int lo = (unsigned int)__shfl_xor((int)(v & 0xffffffffull), m, 64);
    unsigned int hi = (unsigned int)__shfl_xor((int)(v >> 32), m, 64);
    return ((unsigned long long)hi << 32) | lo;
}

// K1: softmax score, threshold, compact candidates into 64-bit sortable keys.
// key = (score_bits << 32) | (0xFFFFFFFF - index)  -> descending key order ==
// descending score, ties broken by ascending index (matches lax.top_k).
__global__ void k_score_compact(const float* __restrict__ conf,
                                unsigned long long* __restrict__ keys,
                                int* __restrict__ rank,
                                int* __restrict__ counter) {
    int i = blockIdx.x * blockDim.x + threadIdx.x;
    if (i >= N_ANCH) return;
    float c0 = conf[2*i+0];
    float c1 = conf[2*i+1];
    float m  = fmaxf(c0, c1);
    float e0 = expf(c0 - m);
    float e1 = expf(c1 - m);
    float s  = e1 / (e0 + e1);
    if (s > CONF_THR) {
        int pos = atomicAdd(counter, 1);
        keys[pos] = ((unsigned long long)__float_as_uint(s) << 32)
                  | (unsigned int)(0xFFFFFFFFu - (unsigned int)i);
        rank[pos] = 0;
    }
}

// K2: rank by counting (sliced). rank[p] = #{keys strictly greater than keys[p]}.
__global__ void k_rank(const unsigned long long* __restrict__ keys,
                       int* __restrict__ rank,
                       const int* __restrict__ counter) {
    int M  = *counter;
    int cb = blockIdx.x * 256;
    if (cb >= M) return;
    int p = cb + threadIdx.x;
    unsigned long long mykey = (p < M) ? keys[p] : 0ull;
    __shared__ unsigned long long sk[256];
    int cnt = 0;
    for (int j0 = blockIdx.y * 256; j0 < M; j0 += 256 * SLICES) {
        int idx = j0 + threadIdx.x;
        sk[threadIdx.x] = (idx < M) ? keys[idx] : 0ull;
        __syncthreads();
        int lim = min(256, M - j0);
#pragma unroll 4
        for (int t = 0; t < lim; ++t)
            cnt += (sk[t] > mykey) ? 1 : 0;
        __syncthreads();
    }
    if (p < M) atomicAdd(&rank[p], cnt);
}

// K3: scatter top-K into sorted slots; decode box + landmarks for selected.
__global__ void k_select(const unsigned long long* __restrict__ keys,
                         const int* __restrict__ rank,
                         const int* __restrict__ counter,
                         const float* __restrict__ loc,
                         const float* __restrict__ land,
                         const float* __restrict__ priors,
                         float* __restrict__ sel_score,
                         float* __restrict__ sel_box,
                         float* __restrict__ sel_lm) {
#pragma clang fp contract(off)
    int M = *counter;
    int p = blockIdx.x * blockDim.x + threadIdx.x;
    if (p >= M) return;
    int r = rank[p];
    if (r >= KCAP) return;
    unsigned long long key = keys[p];
    unsigned int a = 0xFFFFFFFFu - (unsigned int)(key & 0xFFFFFFFFull);
    sel_score[r] = __uint_as_float((unsigned int)(key >> 32));

    float pcx = priors[a*4+0], pcy = priors[a*4+1];
    float pw  = priors[a*4+2], ph  = priors[a*4+3];
    float l0 = loc[a*4+0], l1 = loc[a*4+1], l2 = loc[a*4+2], l3 = loc[a*4+3];
    // replicate reference op order exactly:
    float cx = pcx + (l0 * 0.1f) * pw;
    float cy = pcy + (l1 * 0.1f) * ph;
    float w  = pw * expf(l2 * 0.2f);
    float h  = ph * expf(l3 * 0.2f);
    float x1 = cx - w * 0.5f;
    float y1 = cy - h * 0.5f;
    sel_box[r*4+0] = x1 * 1280.0f;
    sel_box[r*4+1] = y1 * 1280.0f;
    sel_box[r*4+2] = (x1 + w) * 1280.0f;
    sel_box[r*4+3] = (y1 + h) * 1280.0f;
#pragma unroll
    for (int q = 0; q < 5; ++q) {
        float lx = land[a*10 + 2*q + 0];
        float ly = land[a*10 + 2*q + 1];
        sel_lm[r*10 + 2*q + 0] = (pcx + (lx * 0.1f) * pw) * 1280.0f;
        sel_lm[r*10 + 2*q + 1] = (pcy + (ly * 0.1f) * ph) * 1280.0f;
    }
}

// K4: suppression bitmask rows. sup[i][g] bit l set iff j=g*64+l satisfies
// j>i, both valid, iou(b_i,b_j) > NMS_THR.
__global__ void k_sup(const float* __restrict__ sel_box,
                      const int* __restrict__ counter,
                      unsigned long long* __restrict__ sup) {
#pragma clang fp contract(off)
    int i = blockIdx.x;
    int M = *counter;
    int V = min(M, KCAP);
    int lane = threadIdx.x; // 64 threads
    float ax1 = 0.f, ay1 = 0.f, ax2 = 0.f, ay2 = 0.f, aarea = 0.f;
    bool irow = (i < V);
    if (irow) {
        ax1 = sel_box[i*4+0]; ay1 = sel_box[i*4+1];
        ax2 = sel_box[i*4+2]; ay2 = sel_box[i*4+3];
        aarea = (ax2 - ax1) * (ay2 - ay1);
    }
    for (int g = 0; g < 16; ++g) {
        int j = g * 64 + lane;
        bool pred = false;
        if (irow && j < V && j > i) {
            float4 b = reinterpret_cast<const float4*>(sel_box)[j];
            float barea = (b.z - b.x) * (b.w - b.y);
            float ltx = fmaxf(ax1, b.x), lty = fmaxf(ay1, b.y);
            float rbx = fminf(ax2, b.z), rby = fminf(ay2, b.w);
            float wx = fmaxf(rbx - ltx, 0.0f);
            float wy = fmaxf(rby - lty, 0.0f);
            float inter = wx * wy;
            float iou = inter / (aarea + barea - inter + 1e-12f);
            pred = iou > NMS_THR;
        }
        unsigned long long mask = __ballot(pred);
        if (lane == 0) sup[i*16 + g] = mask;
    }
}

// K5: blocked greedy NMS scan (exact forward substitution) + output write.
// 16 chunks of 64 slots. Wave 0 resolves intra-chunk sequentially via shfl;
// all 16 waves apply kept rows' suppression to their keep-word in parallel.
__global__ __launch_bounds__(1024) void k_nms_scan(
        const unsigned long long* __restrict__ sup,
        const int* __restrict__ counter,
        const float* __restrict__ sel_score,
        const float* __restrict__ sel_box,
        const float* __restrict__ sel_lm,
        float* __restrict__ out) {
    __shared__ unsigned long long sup_t[16][1024]; // word-major: sup_t[w][row]
    __shared__ unsigned long long keepw[16];
    __shared__ unsigned long long mshare;
    int tid = threadIdx.x;
    int M = *counter;
    int V = min(M, KCAP);

    // load sup transposed into LDS (coalesced global reads)
    for (int idx = tid; idx < KCAP * 16; idx += 1024) {
        int row = idx >> 4, w = idx & 15;
        sup_t[w][row] = sup[idx];
    }
    // zero-fill rows 1000..1023
    for (int idx = tid; idx < 16 * 24; idx += 1024) {
        int w = idx / 24, row = 1000 + (idx % 24);
        sup_t[w][row] = 0ull;
    }
    if (tid < 16) {
        int lo = tid * 64;
        unsigned long long v;
        if (V >= lo + 64)      v = ~0ull;
        else if (V <= lo)      v = 0ull;
        else                   v = (1ull << (V - lo)) - 1ull;
        keepw[tid] = v;
    }
    __syncthreads();

    int wave = tid >> 6, lane = tid & 63;
    for (int c = 0; c < 16; ++c) {
        if (wave == 0) {
            unsigned long long drow = sup_t[c][c*64 + lane]; // my row's in-chunk bits
            unsigned long long m = keepw[c];
#pragma unroll 1
            for (int i = 0; i < 64; ++i) {
                unsigned long long di = shfl_u64(drow, i);
                unsigned long long gate = 0ull - ((m >> i) & 1ull); // all-ones if slot i kept
                m &= ~(di & gate);
            }
            if (lane == 0) { keepw[c] = m; mshare = m; }
        }
        __syncthreads();
        unsigned long long m = mshare;
        // wave w applies kept rows of chunk c to keep word w (words <= c are no-ops)
        unsigned long long contrib =
            ((m >> lane) & 1ull) ? sup_t[wave][c*64 + lane] : 0ull;
#pragma unroll
        for (int off = 1; off < 64; off <<= 1)
            contrib |= shfl_xor_u64(contrib, off);
        if (lane == 0) keepw[wave] &= ~contrib;
        __syncthreads();
    }

    // write outputs: boxes [0,4000), scores [4000,5000), landms [5000,15000)
    for (int s = tid; s < KCAP; s += 1024) {
        bool kept = ((keepw[s >> 6] >> (s & 63)) & 1ull) != 0ull;
        float4 b = make_float4(0.f, 0.f, 0.f, 0.f);
        float sc = 0.f;
        if (kept) {
            b  = reinterpret_cast<const float4*>(sel_box)[s];
            sc = sel_score[s];
        }
        reinterpret_cast<float4*>(out)[s] = b;
        out[4000 + s] = sc;
#pragma unroll
        for (int q = 0; q < 10; ++q)
            out[5000 + s*10 + q] = kept ? sel_lm[s*10 + q] : 0.f;
    }
}

extern "C" void kernel_launch(void* const* d_in, const int* in_sizes, int n_in,
                              void* d_out, int out_size, void* d_ws, size_t ws_size,
                              hipStream_t stream) {
    const float* loc    = (const float*)d_in[0];
    const float* conf   = (const float*)d_in[1];
    const float* land   = (const float*)d_in[2];
    const float* priors = (const float*)d_in[3];
    float* out = (float*)d_out;
    char* ws = (char*)d_ws;

    int* counter                 = (int*)(ws + OFF_COUNTER);
    unsigned long long* keys     = (unsigned long long*)(ws + OFF_KEYS);
    int* rank                    = (int*)(ws + OFF_RANK);
    float* sel_score             = (float*)(ws + OFF_SCORE);
    float* sel_box               = (float*)(ws + OFF_BOX);
    float* sel_lm                = (float*)(ws + OFF_LM);
    unsigned long long* sup      = (unsigned long long*)(ws + OFF_SUP);

    hipMemsetAsync(ws, 0, 64, stream); // zero candidate counter

    int nb = (N_ANCH + 255) / 256; // 263
    k_score_compact<<<nb, 256, 0, stream>>>(conf, keys, rank, counter);
    k_rank<<<dim3(nb, SLICES), 256, 0, stream>>>(keys, rank, counter);
    k_select<<<nb, 256, 0, stream>>>(keys, rank, counter, loc, land, priors,
                                     sel_score, sel_box, sel_lm);
    k_sup<<<KCAP, 64, 0, stream>>>(sel_box, counter, sup);
    k_nms_scan<<<1, 1024, 0, stream>>>(sup, counter, sel_score, sel_box, sel_lm, out);
}

// Round 3
// 158.951 us; speedup vs baseline: 1.3415x; 1.3415x over previous
//
#include <hip/hip_runtime.h>
#include <stdint.h>

#define N_ANCH 67200
#define KCAP   1000
#define CONF_THR 0.7f
#define NMS_THR  0.4f
#define SLICES 8

// ---- workspace layout (bytes) ----
#define OFF_COUNTER 0
#define OFF_KEYS    64
#define OFF_RANK    (OFF_KEYS + N_ANCH*8)        // 537664
#define OFF_SCORE   (OFF_RANK + N_ANCH*4)        // 806464
#define OFF_BOX     (OFF_SCORE + 1024*4)         // 810560 (16B aligned)
#define OFF_LM      (OFF_BOX + 1024*4*4)         // 826944
#define OFF_SUP     (OFF_LM + 1024*10*4)         // 867904 (8B aligned)
// end = 867904 + 1000*16*8 = 995904 bytes (~0.95 MB of ws)

__device__ inline unsigned long long shfl_xor_u64(unsigned long long v, int m) {
    unsigned int lo = (unsigned int)__shfl_xor((int)(v & 0xffffffffull), m, 64);
    unsigned int hi = (unsigned int)__shfl_xor((int)(v >> 32), m, 64);
    return ((unsigned long long)hi << 32) | lo;
}

// K1: softmax score, threshold, compact candidates into 64-bit sortable keys.
// key = (score_bits << 32) | (0xFFFFFFFF - index)  -> descending key order ==
// descending score, ties broken by ascending index (matches lax.top_k).
__global__ void k_score_compact(const float* __restrict__ conf,
                                unsigned long long* __restrict__ keys,
                                int* __restrict__ rank,
                                int* __restrict__ counter) {
    int i = blockIdx.x * blockDim.x + threadIdx.x;
    if (i >= N_ANCH) return;
    float c0 = conf[2*i+0];
    float c1 = conf[2*i+1];
    float m  = fmaxf(c0, c1);
    float e0 = expf(c0 - m);
    float e1 = expf(c1 - m);
    float s  = e1 / (e0 + e1);
    if (s > CONF_THR) {
        int pos = atomicAdd(counter, 1);
        keys[pos] = ((unsigned long long)__float_as_uint(s) << 32)
                  | (unsigned int)(0xFFFFFFFFu - (unsigned int)i);
        rank[pos] = 0;
    }
}

// K2: rank by counting (sliced). rank[p] = #{keys strictly greater than keys[p]}.
__global__ void k_rank(const unsigned long long* __restrict__ keys,
                       int* __restrict__ rank,
                       const int* __restrict__ counter) {
    int M  = *counter;
    int cb = blockIdx.x * 256;
    if (cb >= M) return;
    int p = cb + threadIdx.x;
    unsigned long long mykey = (p < M) ? keys[p] : 0ull;
    __shared__ unsigned long long sk[256];
    int cnt = 0;
    for (int j0 = blockIdx.y * 256; j0 < M; j0 += 256 * SLICES) {
        int idx = j0 + threadIdx.x;
        sk[threadIdx.x] = (idx < M) ? keys[idx] : 0ull;
        __syncthreads();
        int lim = min(256, M - j0);
#pragma unroll 4
        for (int t = 0; t < lim; ++t)
            cnt += (sk[t] > mykey) ? 1 : 0;
        __syncthreads();
    }
    if (p < M) atomicAdd(&rank[p], cnt);
}

// K3: scatter top-K into sorted slots; decode box + landmarks for selected.
__global__ void k_select(const unsigned long long* __restrict__ keys,
                         const int* __restrict__ rank,
                         const int* __restrict__ counter,
                         const float* __restrict__ loc,
                         const float* __restrict__ land,
                         const float* __restrict__ priors,
                         float* __restrict__ sel_score,
                         float* __restrict__ sel_box,
                         float* __restrict__ sel_lm) {
#pragma clang fp contract(off)
    int M = *counter;
    int p = blockIdx.x * blockDim.x + threadIdx.x;
    if (p >= M) return;
    int r = rank[p];
    if (r >= KCAP) return;
    unsigned long long key = keys[p];
    unsigned int a = 0xFFFFFFFFu - (unsigned int)(key & 0xFFFFFFFFull);
    sel_score[r] = __uint_as_float((unsigned int)(key >> 32));

    float pcx = priors[a*4+0], pcy = priors[a*4+1];
    float pw  = priors[a*4+2], ph  = priors[a*4+3];
    float l0 = loc[a*4+0], l1 = loc[a*4+1], l2 = loc[a*4+2], l3 = loc[a*4+3];
    // replicate reference op order exactly:
    float cx = pcx + (l0 * 0.1f) * pw;
    float cy = pcy + (l1 * 0.1f) * ph;
    float w  = pw * expf(l2 * 0.2f);
    float h  = ph * expf(l3 * 0.2f);
    float x1 = cx - w * 0.5f;
    float y1 = cy - h * 0.5f;
    sel_box[r*4+0] = x1 * 1280.0f;
    sel_box[r*4+1] = y1 * 1280.0f;
    sel_box[r*4+2] = (x1 + w) * 1280.0f;
    sel_box[r*4+3] = (y1 + h) * 1280.0f;
#pragma unroll
    for (int q = 0; q < 5; ++q) {
        float lx = land[a*10 + 2*q + 0];
        float ly = land[a*10 + 2*q + 1];
        sel_lm[r*10 + 2*q + 0] = (pcx + (lx * 0.1f) * pw) * 1280.0f;
        sel_lm[r*10 + 2*q + 1] = (pcy + (ly * 0.1f) * ph) * 1280.0f;
    }
}

// K4: suppression bitmask rows. sup[i][g] bit l set iff j=g*64+l satisfies
// j>i, both valid, iou(b_i,b_j) > NMS_THR.
__global__ void k_sup(const float* __restrict__ sel_box,
                      const int* __restrict__ counter,
                      unsigned long long* __restrict__ sup) {
#pragma clang fp contract(off)
    int i = blockIdx.x;
    int M = *counter;
    int V = min(M, KCAP);
    int lane = threadIdx.x; // 64 threads
    float ax1 = 0.f, ay1 = 0.f, ax2 = 0.f, ay2 = 0.f, aarea = 0.f;
    bool irow = (i < V);
    if (irow) {
        ax1 = sel_box[i*4+0]; ay1 = sel_box[i*4+1];
        ax2 = sel_box[i*4+2]; ay2 = sel_box[i*4+3];
        aarea = (ax2 - ax1) * (ay2 - ay1);
    }
    for (int g = 0; g < 16; ++g) {
        int j = g * 64 + lane;
        bool pred = false;
        if (irow && j < V && j > i) {
            float4 b = reinterpret_cast<const float4*>(sel_box)[j];
            float barea = (b.z - b.x) * (b.w - b.y);
            float ltx = fmaxf(ax1, b.x), lty = fmaxf(ay1, b.y);
            float rbx = fminf(ax2, b.z), rby = fminf(ay2, b.w);
            float wx = fmaxf(rbx - ltx, 0.0f);
            float wy = fmaxf(rby - lty, 0.0f);
            float inter = wx * wy;
            float iou = inter / (aarea + barea - inter + 1e-12f);
            pred = iou > NMS_THR;
        }
        unsigned long long mask = __ballot(pred);
        if (lane == 0) sup[i*16 + g] = mask;
    }
}

// K5: blocked greedy NMS scan (exact forward substitution) + output write.
// 16 chunks of 64 slots; wave c resolves chunk c's 64x64 recurrence on the
// SCALAR pipe (readlane -> SGPR, wave-uniform mask), then all later waves
// apply the kept rows to their keep-word (register-resident) via a shfl_xor
// OR-butterfly. One barrier per chunk. LDS is row-major with XOR-swizzled
// column (col = w ^ (row&15)) so staging writes and reads are conflict-free.
// NOTE: readlane/readfirstlane return *int*; must widen through unsigned int
// or the int->u64 cast sign-extends and corrupts the high word (round-2 bug).
__global__ __launch_bounds__(1024) void k_nms_scan(
        const unsigned long long* __restrict__ sup,
        const int* __restrict__ counter,
        const float* __restrict__ sel_score,
        const float* __restrict__ sel_box,
        const float* __restrict__ sel_lm,
        float* __restrict__ out) {
    __shared__ unsigned long long sup_r[1024][16]; // [row][w ^ (row&15)]
    __shared__ unsigned long long mshare[16];
    __shared__ unsigned long long keep_final[16];
    int tid = threadIdx.x;
    int wave = tid >> 6, lane = tid & 63;
    int M = *counter;
    int V = min(M, KCAP);

    // stage sup into LDS: coalesced global reads, swizzled conflict-free writes
    for (int idx = tid; idx < KCAP * 16; idx += 1024) {
        int r = idx >> 4, w = idx & 15;
        sup_r[r][w ^ (r & 15)] = sup[idx];
    }
    if (tid < 24 * 16) { // zero rows 1000..1023
        int r = 1000 + (tid >> 4), w = tid & 15;
        sup_r[r][w ^ (r & 15)] = 0ull;
    }
    // per-wave keep word, replicated across all lanes of the wave
    unsigned long long kw;
    {
        int lo = wave * 64;
        kw = (V >= lo + 64) ? ~0ull : (V <= lo ? 0ull : ((1ull << (V - lo)) - 1ull));
    }
    __syncthreads();

    for (int c = 0; c < 16; ++c) {
        if (wave == c) {
            // my row's intra-chunk bits (word c of row c*64+lane)
            unsigned long long drow = sup_r[c*64 + lane][c ^ (lane & 15)];
            unsigned int dlo = (unsigned int)drow;
            unsigned int dhi = (unsigned int)(drow >> 32);
            unsigned long long m =
                (((unsigned long long)(unsigned int)__builtin_amdgcn_readfirstlane((unsigned int)(kw >> 32))) << 32)
              |  (unsigned long long)(unsigned int)__builtin_amdgcn_readfirstlane((unsigned int)kw);
#pragma unroll
            for (int i = 0; i < 64; ++i) {
                unsigned long long di =
                    (((unsigned long long)(unsigned int)__builtin_amdgcn_readlane(dhi, i)) << 32)
                  |  (unsigned long long)(unsigned int)__builtin_amdgcn_readlane(dlo, i);
                m = ((m >> i) & 1ull) ? (m & ~di) : m;
            }
            kw = m;
            if (lane == 0) mshare[c] = m;
        }
        __syncthreads();
        if (wave > c) {
            unsigned long long m = mshare[c];
            unsigned long long contrib = ((m >> lane) & 1ull)
                ? sup_r[c*64 + lane][wave ^ (lane & 15)] : 0ull;
#pragma unroll
            for (int off = 1; off < 64; off <<= 1)
                contrib |= shfl_xor_u64(contrib, off); // full OR in every lane
            kw &= ~contrib;
        }
    }
    if (lane == 0) keep_final[wave] = kw;
    __syncthreads();

    // write outputs: boxes [0,4000), scores [4000,5000), landms [5000,15000)
    for (int s = tid; s < KCAP; s += 1024) {
        bool kept = ((keep_final[s >> 6] >> (s & 63)) & 1ull) != 0ull;
        float4 b = make_float4(0.f, 0.f, 0.f, 0.f);
        float sc = 0.f;
        if (kept) {
            b  = reinterpret_cast<const float4*>(sel_box)[s];
            sc = sel_score[s];
        }
        reinterpret_cast<float4*>(out)[s] = b;
        out[4000 + s] = sc;
#pragma unroll
        for (int q = 0; q < 10; ++q)
            out[5000 + s*10 + q] = kept ? sel_lm[s*10 + q] : 0.f;
    }
}

extern "C" void kernel_launch(void* const* d_in, const int* in_sizes, int n_in,
                              void* d_out, int out_size, void* d_ws, size_t ws_size,
                              hipStream_t stream) {
    const float* loc    = (const float*)d_in[0];
    const float* conf   = (const float*)d_in[1];
    const float* land   = (const float*)d_in[2];
    const float* priors = (const float*)d_in[3];
    float* out = (float*)d_out;
    char* ws = (char*)d_ws;

    int* counter                 = (int*)(ws + OFF_COUNTER);
    unsigned long long* keys     = (unsigned long long*)(ws + OFF_KEYS);
    int* rank                    = (int*)(ws + OFF_RANK);
    float* sel_score             = (float*)(ws + OFF_SCORE);
    float* sel_box               = (float*)(ws + OFF_BOX);
    float* sel_lm                = (float*)(ws + OFF_LM);
    unsigned long long* sup      = (unsigned long long*)(ws + OFF_SUP);

    hipMemsetAsync(ws, 0, 64, stream); // zero candidate counter

    int nb = (N_ANCH + 255) / 256; // 263
    k_score_compact<<<nb, 256, 0, stream>>>(conf, keys, rank, counter);
    k_rank<<<dim3(nb, SLICES), 256, 0, stream>>>(keys, rank, counter);
    k_select<<<nb, 256, 0, stream>>>(keys, rank, counter, loc, land, priors,
                                     sel_score, sel_box, sel_lm);
    k_sup<<<KCAP, 64, 0, stream>>>(sel_box, counter, sup);
    k_nms_scan<<<1, 1024, 0, stream>>>(sup, counter, sel_score, sel_box, sel_lm, out);
}